// Round 1
// baseline (487.797 us; speedup 1.0000x reference)
//
#include <hip/hip_runtime.h>
#include <hip/hip_bf16.h>
#include <cstdint>

#define N_NODES 50000
#define N_EDGES 500000
#define ND 128
#define ED 64
#define OD 128

typedef __attribute__((ext_vector_type(8))) short short8;
typedef __attribute__((ext_vector_type(4))) float f32x4;

__device__ __forceinline__ unsigned short f2bf(float f) {
    union { float f; unsigned u; } c; c.f = f;
    unsigned u = c.u;
    unsigned r = (u + 0x7FFFu + ((u >> 16) & 1u)) >> 16;  // RNE
    return (unsigned short)r;
}
__device__ __forceinline__ float bf2f(unsigned short s) {
    union { unsigned u; float f; } c; c.u = ((unsigned)s) << 16;
    return c.f;
}

// ---------------------------------------------------------------------------
// Kernel 0: build bf16 transposed weight panels in workspace.
//   wbtNP[n][k], n in [0,256), k in [0,128):  n<128 ? W[k][n] : W[128+k][n-128]
//   wbtE [n][k], n in [0,128), k in [0,64):   W[256+k][n]
// ---------------------------------------------------------------------------
__global__ void prep_kernel(const float* __restrict__ W,
                            unsigned short* __restrict__ wbtNP,
                            unsigned short* __restrict__ wbtE) {
    int g = blockIdx.x * 256 + threadIdx.x;   // grid covers exactly 40960
    if (g < 256 * 128) {
        int n = g >> 7, k = g & 127;
        float v = (n < 128) ? W[k * OD + n] : W[(128 + k) * OD + (n - 128)];
        wbtNP[n * 128 + k] = f2bf(v);
    } else {
        int h = g - 256 * 128;
        int n = h >> 6, k = h & 63;
        wbtE[n * 64 + k] = f2bf(W[(256 + k) * OD + n]);
    }
}

// ---------------------------------------------------------------------------
// Kernel 1: P[m][0:128] = nf[m] @ W1 ; P[m][128:256] = nf[m] @ W2   (bf16 out)
// BM=64 rows/block, 512 threads (8 waves: 4 M-groups x 2 N-groups), K=128.
// ---------------------------------------------------------------------------
__launch_bounds__(512)
__global__ void nodeproj_kernel(const float* __restrict__ nf,
                                const unsigned short* __restrict__ wbtNP,
                                unsigned short* __restrict__ P) {
    __shared__ char lds[16384 + 65536];  // A: [64][128] bf16 swz ; B: [256][128] bf16 swz
    int tid = threadIdx.x;
    int m0 = blockIdx.x * 64;

    // stage A (node_feats rows, f32 -> bf16), swizzled
    for (int i = 0; i < 4; ++i) {
        int idx = tid + i * 512;
        int row = idx >> 5, c4 = idx & 31;       // c4: which float4 of the 128-col row
        int m = m0 + row;
        float4 v = make_float4(0.f, 0.f, 0.f, 0.f);
        if (m < N_NODES) v = *(const float4*)(nf + m * ND + c4 * 4);
        uint2 pk;
        pk.x = (unsigned)f2bf(v.x) | ((unsigned)f2bf(v.y) << 16);
        pk.y = (unsigned)f2bf(v.z) | ((unsigned)f2bf(v.w) << 16);
        int byte = (row * 256 + c4 * 8) ^ ((row & 7) << 4);
        *(uint2*)(lds + byte) = pk;
    }
    // stage B (wbtNP bf16), swizzled
    {
        const uint2* wsrc = (const uint2*)wbtNP;
        for (int i = 0; i < 16; ++i) {
            int idx = tid + i * 512;
            int row = idx >> 5, c4 = idx & 31;
            uint2 v = wsrc[row * 32 + c4];
            int byte = 16384 + ((row * 256 + c4 * 8) ^ ((row & 7) << 4));
            *(uint2*)(lds + byte) = v;
        }
    }
    __syncthreads();

    int lane = tid & 63, wid = tid >> 6;
    int wm = wid >> 1;     // 0..3 -> 16-row strip
    int wn = wid & 1;      // 0..1 -> 128-col half
    f32x4 acc[8];
#pragma unroll
    for (int i = 0; i < 8; ++i) acc[i] = (f32x4){0.f, 0.f, 0.f, 0.f};

    int arow = 16 * wm + (lane & 15);
    int abase = arow * 256;
    int aswz = (arow & 7) << 4;
#pragma unroll
    for (int kc = 0; kc < 4; ++kc) {
        int kb = kc * 64 + ((lane >> 4) << 4);
        short8 a = *(const short8*)(lds + ((abase + kb) ^ aswz));
#pragma unroll
        for (int nt = 0; nt < 8; ++nt) {
            int brow = 128 * wn + 16 * nt + (lane & 15);
            short8 b = *(const short8*)(lds + 16384 + ((brow * 256 + kb) ^ ((brow & 7) << 4)));
            acc[nt] = __builtin_amdgcn_mfma_f32_16x16x32_bf16(a, b, acc[nt], 0, 0, 0);
        }
    }

    // epilogue: direct bf16 stores (C/D: col = lane&15, row = 4*(lane>>4)+reg)
    int mbase = m0 + 16 * wm + ((lane >> 4) << 2);
    int colbase = 128 * wn + (lane & 15);
#pragma unroll
    for (int nt = 0; nt < 8; ++nt) {
#pragma unroll
        for (int r = 0; r < 4; ++r) {
            int mm = mbase + r;
            if (mm < N_NODES) P[mm * 256 + colbase + 16 * nt] = f2bf(acc[nt][r]);
        }
    }
}

// ---------------------------------------------------------------------------
// Kernel 2: out[e] = ef[e] @ W3 + P[src[e]][0:128] + P[dst[e]][128:256] + b
// BM=64 edges/block, 256 threads (4 waves, 16 rows each), K=64.
// ---------------------------------------------------------------------------
__launch_bounds__(256)
__global__ void edge_kernel(const float* __restrict__ ef,
                            const int* __restrict__ src,
                            const int* __restrict__ dst,
                            const unsigned short* __restrict__ wbtE,
                            const unsigned short* __restrict__ P,
                            const float* __restrict__ bias,
                            float* __restrict__ out) {
    __shared__ char lds[8192 + 16384 + 32768];  // E[64][64]bf16 swz ; W3t[128][64]bf16 swz ; Cbuf[64][128]f32 swz
    int tid = threadIdx.x;
    int e0 = blockIdx.x * 64;

    // stage E (edge_feats rows, f32 -> bf16), swizzled. 64 rows x 16 float4.
    for (int i = 0; i < 4; ++i) {
        int idx = tid + i * 256;
        int row = idx >> 4, c4 = idx & 15;
        int e = e0 + row;
        float4 v = make_float4(0.f, 0.f, 0.f, 0.f);
        if (e < N_EDGES) v = *(const float4*)(ef + e * ED + c4 * 4);
        uint2 pk;
        pk.x = (unsigned)f2bf(v.x) | ((unsigned)f2bf(v.y) << 16);
        pk.y = (unsigned)f2bf(v.z) | ((unsigned)f2bf(v.w) << 16);
        int byte = (row * 128 + c4 * 8) ^ ((row & 7) << 4);
        *(uint2*)(lds + byte) = pk;
    }
    // stage W3t (bf16), swizzled. 128 rows x 8 uint2.
    {
        const uint2* wsrc = (const uint2*)wbtE;
        for (int i = 0; i < 8; ++i) {
            int idx = tid + i * 256;
            int row = idx >> 4, c4 = idx & 15;
            uint2 v = wsrc[row * 16 + c4];
            int byte = 8192 + ((row * 128 + c4 * 8) ^ ((row & 7) << 4));
            *(uint2*)(lds + byte) = v;
        }
    }
    __syncthreads();

    int lane = tid & 63, wid = tid >> 6;
    f32x4 acc[8];
#pragma unroll
    for (int i = 0; i < 8; ++i) acc[i] = (f32x4){0.f, 0.f, 0.f, 0.f};

    int arow = 16 * wid + (lane & 15);
#pragma unroll
    for (int kc = 0; kc < 2; ++kc) {
        int kb = kc * 64 + ((lane >> 4) << 4);
        short8 a = *(const short8*)(lds + ((arow * 128 + kb) ^ ((arow & 7) << 4)));
#pragma unroll
        for (int nt = 0; nt < 8; ++nt) {
            int brow = 16 * nt + (lane & 15);
            short8 b = *(const short8*)(lds + 8192 + ((brow * 128 + kb) ^ ((brow & 7) << 4)));
            acc[nt] = __builtin_amdgcn_mfma_f32_16x16x32_bf16(a, b, acc[nt], 0, 0, 0);
        }
    }

    // acc -> Cbuf (f32), swizzled so the 4 rows per lane hit distinct banks
    {
        int rbase = 16 * wid + ((lane >> 4) << 2);
        int col = lane & 15;
#pragma unroll
        for (int nt = 0; nt < 8; ++nt) {
#pragma unroll
            for (int r = 0; r < 4; ++r) {
                int row = rbase + r;
                int cbyte = (col + 16 * nt) * 4;
                int byte = 24576 + ((row * 512 + cbyte) ^ (((row >> 2) & 3) << 4));
                *(float*)(lds + byte) = acc[nt][r];
            }
        }
    }
    __syncthreads();

    // epilogue: coalesced gather-add-store. 32 lanes per row, 4 cols/lane.
    int l32 = tid & 31;
    float4 bv = *(const float4*)(bias + l32 * 4);
    const char* Pb = (const char*)P;
#pragma unroll
    for (int it = 0; it < 8; ++it) {
        int row = (tid >> 5) + it * 8;
        int e = e0 + row;
        if (e < N_EDGES) {
            float4 cb = *(const float4*)(lds + 24576 + ((row * 512 + l32 * 16) ^ (((row >> 2) & 3) << 4)));
            int s = src[e], d = dst[e];
            uint2 p1 = *(const uint2*)(Pb + s * 512 + l32 * 8);
            uint2 p2 = *(const uint2*)(Pb + d * 512 + 256 + l32 * 8);
            float4 o;
            o.x = cb.x + bv.x + bf2f((unsigned short)(p1.x & 0xFFFF)) + bf2f((unsigned short)(p2.x & 0xFFFF));
            o.y = cb.y + bv.y + bf2f((unsigned short)(p1.x >> 16))   + bf2f((unsigned short)(p2.x >> 16));
            o.z = cb.z + bv.z + bf2f((unsigned short)(p1.y & 0xFFFF)) + bf2f((unsigned short)(p2.y & 0xFFFF));
            o.w = cb.w + bv.w + bf2f((unsigned short)(p1.y >> 16))   + bf2f((unsigned short)(p2.y >> 16));
            *(float4*)(out + e * OD + l32 * 4) = o;
        }
    }
}

// ---------------------------------------------------------------------------
// Fallback (ws too small): naive fp32, one thread per output element.
// ---------------------------------------------------------------------------
__global__ void naive_kernel(const float* __restrict__ nf, const float* __restrict__ ef,
                             const int* __restrict__ src, const int* __restrict__ dst,
                             const float* __restrict__ W, const float* __restrict__ bias,
                             float* __restrict__ out) {
    long g = (long)blockIdx.x * 256 + threadIdx.x;
    if (g >= (long)N_EDGES * OD) return;
    int e = (int)(g >> 7), j = (int)(g & 127);
    int s = src[e], d = dst[e];
    float sum = bias[j];
    for (int k = 0; k < ND; ++k) sum += nf[s * ND + k] * W[k * OD + j];
    for (int k = 0; k < ND; ++k) sum += nf[d * ND + k] * W[(ND + k) * OD + j];
    for (int k = 0; k < ED; ++k) sum += ef[e * ED + k] * W[(2 * ND + k) * OD + j];
    out[g] = sum;
}

extern "C" void kernel_launch(void* const* d_in, const int* in_sizes, int n_in,
                              void* d_out, int out_size, void* d_ws, size_t ws_size,
                              hipStream_t stream) {
    const float* nf  = (const float*)d_in[0];
    const float* ef  = (const float*)d_in[1];
    const int*   src = (const int*)d_in[2];
    const int*   dst = (const int*)d_in[3];
    const float* W   = (const float*)d_in[4];
    const float* bias= (const float*)d_in[5];
    float* out = (float*)d_out;

    const size_t need = 65536 + 16384 + (size_t)N_NODES * 256 * 2;
    if (ws_size < need) {
        long total = (long)N_EDGES * OD;
        naive_kernel<<<(int)((total + 255) / 256), 256, 0, stream>>>(nf, ef, src, dst, W, bias, out);
        return;
    }
    unsigned short* wbtNP = (unsigned short*)d_ws;
    unsigned short* wbtE  = (unsigned short*)((char*)d_ws + 65536);
    unsigned short* P     = (unsigned short*)((char*)d_ws + 81920);

    prep_kernel<<<160, 256, 0, stream>>>(W, wbtNP, wbtE);
    nodeproj_kernel<<<(N_NODES + 63) / 64, 512, 0, stream>>>(nf, wbtNP, P);
    edge_kernel<<<(N_EDGES + 63) / 64, 256, 0, stream>>>(ef, src, dst, wbtE, P, bias, out);
}